// Round 6
// baseline (951.871 us; speedup 1.0000x reference)
//
#include <hip/hip_runtime.h>
#include <hip/hip_bf16.h>

#define B_ 2048
#define T_ 512
#define DIN_ 32
#define DH_ 96
#define NG_ 384
#define E_ 6

#define BPB 8      // batch rows per block
#define HP 104     // fp16 elems per h row (96 + 8 pad, keeps 16B alignment)
#define GS 12      // words per sgate row (96 B? no: 48 B) — 8 data + 4 pad

typedef __attribute__((ext_vector_type(8))) _Float16 f16x8;
typedef __attribute__((ext_vector_type(4))) float f32x4;

#if defined(__has_builtin)
# if __has_builtin(__builtin_amdgcn_exp2f)
#  define EXP2F(x) __builtin_amdgcn_exp2f(x)
# endif
# if __has_builtin(__builtin_amdgcn_rcpf)
#  define RCPF(x) __builtin_amdgcn_rcpf(x)
# endif
#endif
#ifndef EXP2F
# define EXP2F(x) exp2f(x)
#endif
#ifndef RCPF
# define RCPF(x) (1.0f/(x))
#endif

__device__ __forceinline__ float sigf(float x) {
    return RCPF(1.0f + EXP2F(x * -1.44269504f));
}
__device__ __forceinline__ float tanhf_(float x) {
    return 1.0f - 2.0f * RCPF(1.0f + EXP2F(x * 2.88539008f));
}

// fp32[8] -> f16x8 (RNE via v_cvt_f16_f32)
__device__ __forceinline__ f16x8 cvt8(float4 a, float4 b) {
    f16x8 r;
    r[0] = (_Float16)a.x; r[1] = (_Float16)a.y; r[2] = (_Float16)a.z; r[3] = (_Float16)a.w;
    r[4] = (_Float16)b.x; r[5] = (_Float16)b.y; r[6] = (_Float16)b.z; r[7] = (_Float16)b.w;
    return r;
}
__device__ __forceinline__ f16x8 cvt8p(const float* p) {
    return cvt8(*(const float4*)p, *(const float4*)(p + 4));
}

// LDS-only barrier: waits lgkmcnt(0) but NOT vmcnt, so outstanding global
// stores/loads don't serialize the recurrence.
__device__ __forceinline__ void lds_barrier() {
    asm volatile("s_waitcnt lgkmcnt(0)\n\ts_barrier" ::: "memory");
}

// ---------------- Kernel A: fused LSTM ----------------
// 256 blocks x 768 threads (12 waves, 3/SIMD). Block owns 8 batch rows.
// Phase 1 (MFMA, waves 0-7 only => 2 MFMA-waves/SIMD balanced): wave w
//   computes gate-tiles {3w..3w+2} (tile tau: gate tau/6, unit16 tau%6),
//   C init = bias, writes raw gates to sgate[gcol*GS + b] (ds_write_b128,
//   quads 0-1; A rows 8-15 are zero padding). GS=12 spreads start banks.
// Phase 2 (epilogue, all 12 waves): lane tid -> (u=tid>>3, b=tid&7) reads
//   i/f/g/o from sgate (<=2-way), activations, writes fp16 h to sh[buf^1].
// Phase 3 (coop store): 384 lanes stream h(t) LDS->global as coalesced dwords.
__global__ __launch_bounds__(768, 1) void lstm_kernel(
    const float* __restrict__ x, const int* __restrict__ lengths,
    const float* __restrict__ Wih, const float* __restrict__ Whh,
    const float* __restrict__ bih, const float* __restrict__ bhh,
    _Float16* __restrict__ Hout, float* __restrict__ hT)
{
    __shared__ float sgate[NG_ * GS];       // 18432 B, raw gates [gcol][b + pad]
    __shared__ _Float16 sh[2][16 * HP];     // 6656 B, h double buffer [b][u]

    const int tid  = threadIdx.x;
    const int bb   = blockIdx.x * BPB;
    const int wave = tid >> 6;
    const int lane = tid & 63;
    const int col  = lane & 15;
    const int quad = lane >> 4;
    const bool mf  = wave < 8;

    // ---- MFMA role: 3 gate tiles for waves 0-7
    int gc[3] = {0, 0, 0};
    float bias[3] = {0.f, 0.f, 0.f};
    f16x8 wh[3][3], wi[3];
    if (mf) {
#pragma unroll
        for (int j = 0; j < 3; ++j) {
            const int tau = wave * 3 + j;
            const int g = tau / 6, u6 = tau % 6;
            const int gcj = g * DH_ + u6 * 16 + col;   // gate column 0..383
            gc[j] = gcj;
#pragma unroll
            for (int kf = 0; kf < 3; ++kf)
                wh[j][kf] = cvt8p(Whh + gcj * DH_ + kf * 32 + quad * 8);
            wi[j] = cvt8p(Wih + gcj * DIN_ + quad * 8);
            bias[j] = bih[gcj] + bhh[gcj];
        }
    }

    // ---- epilogue role: one (unit, batch) pair per lane
    const int eu = tid >> 3;          // 0..95
    const int eb = tid & 7;           // 0..7
    float c1 = 0.f, hk1 = 0.f;
    const int len1 = lengths[bb + eb];

    // ---- coop-store role
    const bool st_act = tid < 384;
    const int sb = tid / 48;                  // batch row 0..7
    const int su = (tid % 48) * 2;            // unit pair
    _Float16* Hst = Hout + ((long long)(bb + sb) * T_) * DH_ + su;

    // ---- x prefetch (A-fragment; rows 8-15 padding, clamp address)
    const int xb = (bb + col < B_) ? (bb + col) : (B_ - 1);
    const float* xp = x + ((long long)xb * T_) * DIN_ + quad * 8;
    float4 xc0, xc1;
    if (mf) { xc0 = *(const float4*)xp; xc1 = *(const float4*)(xp + 4); }

    // zero h buffers (rows 8-15 stay zero forever)
    {
        _Float16* shf = &sh[0][0];
        for (int i = tid; i < 2 * 16 * HP; i += 768) shf[i] = (_Float16)0.f;
    }
    __syncthreads();

    for (int t = 0; t < T_; ++t) {
        const int buf = t & 1;

        // ---------- phase 1: MFMA (waves 0-7) ----------
        const float* xpn = xp;
        if (mf) {
            const _Float16* hrow = &sh[buf][col * HP];
            f16x8 h0 = *(const f16x8*)(hrow + 0  + quad * 8);
            f16x8 h1 = *(const f16x8*)(hrow + 32 + quad * 8);
            f16x8 h2 = *(const f16x8*)(hrow + 64 + quad * 8);

            // prefetch x(t+1)
            xpn = (t + 1 < T_) ? (xp + DIN_) : xp;
            float4 xn0 = *(const float4*)xpn;
            float4 xn1 = *(const float4*)(xpn + 4);

            f16x8 xa = cvt8(xc0, xc1);

#pragma unroll
            for (int j = 0; j < 3; ++j) {
                f32x4 a = {bias[j], bias[j], bias[j], bias[j]};
                a = __builtin_amdgcn_mfma_f32_16x16x32_f16(h0, wh[j][0], a, 0, 0, 0);
                a = __builtin_amdgcn_mfma_f32_16x16x32_f16(h1, wh[j][1], a, 0, 0, 0);
                a = __builtin_amdgcn_mfma_f32_16x16x32_f16(h2, wh[j][2], a, 0, 0, 0);
                a = __builtin_amdgcn_mfma_f32_16x16x32_f16(xa, wi[j],    a, 0, 0, 0);
                if (quad < 2)   // rows 0-7 real batch; 8-15 padding
                    *(f32x4*)&sgate[gc[j] * GS + quad * 4] = a;
            }
            xc0 = xn0; xc1 = xn1;
        }
        lds_barrier();   // gates visible

        // ---------- phase 2: epilogue (one pair per lane, all waves) ----------
        {
            float iv = sgate[(0 * DH_ + eu) * GS + eb];
            float fv = sgate[(1 * DH_ + eu) * GS + eb];
            float gv = sgate[(2 * DH_ + eu) * GS + eb];
            float ov = sgate[(3 * DH_ + eu) * GS + eb];
            float cn = sigf(fv) * c1 + sigf(iv) * tanhf_(gv);
            float hn = sigf(ov) * tanhf_(cn);
            const bool m = t < len1;
            c1  = m ? cn : c1;
            hk1 = m ? hn : hk1;
            sh[buf ^ 1][eb * HP + eu] = (_Float16)hk1;
        }
        lds_barrier();   // h(t) visible

        // ---------- phase 3: coop H store ----------
        if (st_act) {
            unsigned v = *(const unsigned*)&sh[buf ^ 1][sb * HP + su];
            *(unsigned*)Hst = v;
            Hst += DH_;
        }

        xp = xpn;
    }

    hT[(bb + eb) * DH_ + eu] = hk1;
}

// ---------------- Kernel B: per-batch Q, qk = (Wk^T Q)/sqrt(DH), qb = (Q.bk)/sqrt(DH)
__global__ __launch_bounds__(128) void qk_kernel(
    const float* __restrict__ hT, const float* __restrict__ Wq,
    const float* __restrict__ bq, const float* __restrict__ Wk,
    const float* __restrict__ bk, float* __restrict__ qk_out,
    float* __restrict__ qb_out)
{
    __shared__ float shT[DH_], sQ[DH_];
    const int b = blockIdx.x, tid = threadIdx.x;
    const float scale = 0.10206207262f; // 1/sqrt(96)
    if (tid < DH_) shT[tid] = hT[b * DH_ + tid];
    __syncthreads();
    if (tid < DH_) {
        float acc = bq[tid];
        const float* wr = Wq + tid * DH_;
        for (int d = 0; d < DH_; d += 4) {
            float4 w4 = *(const float4*)(wr + d);
            acc += w4.x * shT[d] + w4.y * shT[d + 1] + w4.z * shT[d + 2] + w4.w * shT[d + 3];
        }
        sQ[tid] = acc;
    }
    __syncthreads();
    if (tid < DH_) {
        float acc = 0.f;
        for (int j = 0; j < DH_; ++j) acc += Wk[j * DH_ + tid] * sQ[j];
        qk_out[b * DH_ + tid] = acc * scale;
    }
    if (tid == 0) {
        float acc = 0.f;
        for (int d = 0; d < DH_; ++d) acc += sQ[d] * bk[d];
        qb_out[b] = acc * scale;
    }
}

// ---------------- Kernel C: logits/softmax/ctx + MoE head. One block per batch.
__global__ __launch_bounds__(512) void attn_moe_kernel(
    const _Float16* __restrict__ H, const float* __restrict__ hT,
    const float* __restrict__ qk, const float* __restrict__ qb,
    const int* __restrict__ lengths,
    const float* __restrict__ Wv, const float* __restrict__ bv,
    const float* __restrict__ Wg, const float* __restrict__ bg,
    const float* __restrict__ We1, const float* __restrict__ be1,
    const float* __restrict__ We2, const float* __restrict__ be2,
    float* __restrict__ yhat_out, float* __restrict__ alpha_out,
    float* __restrict__ gl_out)
{
    __shared__ float salpha[T_];
    __shared__ float sqk[DH_];
    __shared__ float spart[4 * DH_];
    __shared__ float sfeats[2 * DH_];
    __shared__ float sh1[2][DH_];
    __shared__ float sred[8], ssum[8];
    __shared__ float sgl[E_];
    __shared__ float spi[2];
    __shared__ int stopi[2];

    const int b = blockIdx.x, tid = threadIdx.x;
    const int len = lengths[b];
    if (tid < DH_) sqk[tid] = qk[b * DH_ + tid];
    const float qbv = qb[b];
    __syncthreads();

    // logits: thread t
    const _Float16* hr = H + ((long long)b * T_ + tid) * DH_;
    float l = qbv;
#pragma unroll
    for (int u = 0; u < DH_; u += 8) {
        f16x8 hv = *(const f16x8*)(hr + u);
        float4 qa = *(const float4*)&sqk[u];
        float4 qc = *(const float4*)&sqk[u + 4];
        l += (float)hv[0] * qa.x + (float)hv[1] * qa.y
           + (float)hv[2] * qa.z + (float)hv[3] * qa.w
           + (float)hv[4] * qc.x + (float)hv[5] * qc.y
           + (float)hv[6] * qc.z + (float)hv[7] * qc.w;
    }
    const bool valid = tid < len;
    float lv = valid ? l : -1e30f;

    float m = lv;
    for (int off = 32; off; off >>= 1) m = fmaxf(m, __shfl_xor(m, off));
    if ((tid & 63) == 0) sred[tid >> 6] = m;
    __syncthreads();
    m = sred[0];
#pragma unroll
    for (int i = 1; i < 8; ++i) m = fmaxf(m, sred[i]);

    float e = valid ? EXP2F((l - m) * 1.44269504f) : 0.f;
    float s = e;
    for (int off = 32; off; off >>= 1) s += __shfl_xor(s, off);
    if ((tid & 63) == 0) ssum[tid >> 6] = s;
    __syncthreads();
    s = ssum[0];
#pragma unroll
    for (int i = 1; i < 8; ++i) s += ssum[i];

    const float alpha = e * RCPF(s);
    salpha[tid] = alpha;
    alpha_out[(long long)b * T_ + tid] = alpha;
    __syncthreads();

    // ctx raw partials: 4 t-chunks x 96 units
    if (tid < 4 * DH_) {
        const int s4 = tid / DH_, u = tid - s4 * DH_;
        float acc = 0.f;
        const _Float16* hc = H + ((long long)b * T_) * DH_ + u;
        for (int t = s4 * 128; t < s4 * 128 + 128; ++t)
            acc += salpha[t] * (float)hc[t * DH_];
        spart[s4 * DH_ + u] = acc;
    }
    __syncthreads();
    if (tid < DH_) {
        float craw = spart[tid] + spart[DH_ + tid] + spart[2 * DH_ + tid] + spart[3 * DH_ + tid];
        spart[tid] = craw;
    }
    __syncthreads();
    if (tid < DH_) {
        float acc = bv[tid];
        const float* wr = Wv + tid * DH_;
        for (int u = 0; u < DH_; u += 4) {
            float4 w4 = *(const float4*)(wr + u);
            acc += w4.x * spart[u] + w4.y * spart[u + 1] + w4.z * spart[u + 2] + w4.w * spart[u + 3];
        }
        sfeats[tid] = acc;             // ctx
        sfeats[DH_ + tid] = hT[b * DH_ + tid];
    }
    __syncthreads();

    // gate logits: 6 experts x 32 lanes, 6 f-elems per lane
    if (tid < 192) {
        const int e6 = tid >> 5, cc = tid & 31;
        float p = 0.f;
        const float* wg = Wg + e6 * 2 * DH_;
#pragma unroll
        for (int j = 0; j < 6; ++j) p += wg[cc * 6 + j] * sfeats[cc * 6 + j];
        for (int off = 16; off; off >>= 1) p += __shfl_xor(p, off);
        if (cc == 0) {
            float g = p + bg[e6];
            sgl[e6] = g;
            gl_out[b * E_ + e6] = g;
        }
    }
    __syncthreads();

    if (tid == 0) {
        int i0 = 0; float v0 = sgl[0];
        for (int ee = 1; ee < E_; ++ee) if (sgl[ee] > v0) { v0 = sgl[ee]; i0 = ee; }
        int i1 = -1; float v1 = -1e30f;
        for (int ee = 0; ee < E_; ++ee) {
            if (ee == i0) continue;
            if (sgl[ee] > v1) { v1 = sgl[ee]; i1 = ee; }
        }
        float e1 = EXP2F((v1 - v0) * 1.44269504f);
        float inv = RCPF(1.f + e1);
        spi[0] = inv; spi[1] = e1 * inv;
        stopi[0] = i0; stopi[1] = i1;
    }
    __syncthreads();

    // expert hidden for the 2 selected experts
    if (tid < 192) {
        const int e2 = tid / DH_, u = tid - e2 * DH_;
        const int ex = stopi[e2];
        float acc = be1[ex * DH_ + u];
        const float* w = We1 + ((long long)ex * DH_ + u) * (2 * DH_);
        for (int f = 0; f < 2 * DH_; f += 4) {
            float4 w4 = *(const float4*)(w + f);
            acc += w4.x * sfeats[f] + w4.y * sfeats[f + 1] + w4.z * sfeats[f + 2] + w4.w * sfeats[f + 3];
        }
        sh1[e2][u] = fmaxf(acc, 0.f);
    }
    __syncthreads();

    if (tid == 0) {
        float outs[2];
#pragma unroll
        for (int e2 = 0; e2 < 2; ++e2) {
            const int ex = stopi[e2];
            float a = be2[ex];
            for (int u = 0; u < DH_; ++u) a += sh1[e2][u] * We2[ex * DH_ + u];
            outs[e2] = a;
        }
        yhat_out[b] = spi[0] * outs[0] + spi[1] * outs[1];
    }
}

extern "C" void kernel_launch(void* const* d_in, const int* in_sizes, int n_in,
                              void* d_out, int out_size, void* d_ws, size_t ws_size,
                              hipStream_t stream) {
    const float* x   = (const float*)d_in[0];
    const int* lengths = (const int*)d_in[1];
    // d_in[2] = mask (recomputed from lengths)
    const float* Wih = (const float*)d_in[3];
    const float* Whh = (const float*)d_in[4];
    const float* bih = (const float*)d_in[5];
    const float* bhh = (const float*)d_in[6];
    const float* Wq  = (const float*)d_in[7];
    const float* bq  = (const float*)d_in[8];
    const float* Wk  = (const float*)d_in[9];
    const float* bk  = (const float*)d_in[10];
    const float* Wv  = (const float*)d_in[11];
    const float* bv  = (const float*)d_in[12];
    const float* Wg  = (const float*)d_in[13];
    const float* bg  = (const float*)d_in[14];
    const float* We1 = (const float*)d_in[15];
    const float* be1 = (const float*)d_in[16];
    const float* We2 = (const float*)d_in[17];
    const float* be2 = (const float*)d_in[18];

    float* yhat  = (float*)d_out;
    float* alpha = yhat + B_;
    float* gl    = alpha + (size_t)B_ * T_;

    char* ws = (char*)d_ws;
    _Float16* Hws = (_Float16*)ws;                                   // B*T*96 fp16
    float* hTws = (float*)(ws + (size_t)B_ * T_ * DH_ * 2);          // B*96 f32
    float* qkws = hTws + (size_t)B_ * DH_;                           // B*96 f32
    float* qbws = qkws + (size_t)B_ * DH_;                           // B f32

    lstm_kernel<<<dim3(B_ / BPB), dim3(768), 0, stream>>>(
        x, lengths, Wih, Whh, bih, bhh, Hws, hTws);
    qk_kernel<<<dim3(B_), dim3(128), 0, stream>>>(
        hTws, Wq, bq, Wk, bk, qkws, qbws);
    attn_moe_kernel<<<dim3(B_), dim3(512), 0, stream>>>(
        Hws, hTws, qkws, qbws, lengths, Wv, bv, Wg, bg,
        We1, be1, We2, be2, yhat, alpha, gl);
}

// Round 7
// 804.054 us; speedup vs baseline: 1.1838x; 1.1838x over previous
//
#include <hip/hip_runtime.h>
#include <hip/hip_bf16.h>

#define B_ 2048
#define T_ 512
#define DIN_ 32
#define DH_ 96
#define NG_ 384
#define E_ 6

#define BPB 8      // batch rows per block
#define HP 104     // fp16 elems per h row (96 + 8 pad, keeps 16B alignment)
#define GS 8       // words per sgate row

typedef __attribute__((ext_vector_type(8))) _Float16 f16x8;
typedef __attribute__((ext_vector_type(4))) float f32x4;

#if defined(__has_builtin)
# if __has_builtin(__builtin_amdgcn_exp2f)
#  define EXP2F(x) __builtin_amdgcn_exp2f(x)
# endif
# if __has_builtin(__builtin_amdgcn_rcpf)
#  define RCPF(x) __builtin_amdgcn_rcpf(x)
# endif
#endif
#ifndef EXP2F
# define EXP2F(x) exp2f(x)
#endif
#ifndef RCPF
# define RCPF(x) (1.0f/(x))
#endif

__device__ __forceinline__ float sigf(float x) {
    return RCPF(1.0f + EXP2F(x * -1.44269504f));
}
__device__ __forceinline__ float tanhf_(float x) {
    return 1.0f - 2.0f * RCPF(1.0f + EXP2F(x * 2.88539008f));
}

__device__ __forceinline__ f16x8 cvt8(float4 a, float4 b) {
    f16x8 r;
    r[0] = (_Float16)a.x; r[1] = (_Float16)a.y; r[2] = (_Float16)a.z; r[3] = (_Float16)a.w;
    r[4] = (_Float16)b.x; r[5] = (_Float16)b.y; r[6] = (_Float16)b.z; r[7] = (_Float16)b.w;
    return r;
}
__device__ __forceinline__ f16x8 cvt8p(const float* p) {
    return cvt8(*(const float4*)p, *(const float4*)(p + 4));
}

// LDS-only barrier: waits lgkmcnt(0) but NOT vmcnt (outstanding global stores
// don't serialize the recurrence).
__device__ __forceinline__ void lds_barrier() {
    asm volatile("s_waitcnt lgkmcnt(0)\n\ts_barrier" ::: "memory");
}

// ---------------- sort kernels: counting sort of batches by length ----------
__global__ __launch_bounds__(512) void sort_zero_kernel(int* __restrict__ bins) {
    bins[threadIdx.x] = 0;
}
__global__ __launch_bounds__(256) void sort_count_kernel(
    const int* __restrict__ lengths, int* __restrict__ bins) {
    const int b = blockIdx.x * 256 + threadIdx.x;
    atomicAdd(&bins[lengths[b] - 1], 1);
}
__global__ __launch_bounds__(512) void sort_scan_kernel(
    const int* __restrict__ bins, int* __restrict__ offs) {
    __shared__ int s[512];
    const int tid = threadIdx.x;
    s[tid] = bins[tid];
    __syncthreads();
    for (int d = 1; d < 512; d <<= 1) {
        int v = (tid >= d) ? s[tid - d] : 0;
        __syncthreads();
        s[tid] += v;
        __syncthreads();
    }
    offs[tid] = s[tid] - bins[tid];   // exclusive prefix
}
__global__ __launch_bounds__(256) void sort_place_kernel(
    const int* __restrict__ lengths, int* __restrict__ offs,
    int* __restrict__ perm) {
    const int b = blockIdx.x * 256 + threadIdx.x;
    const int pos = atomicAdd(&offs[lengths[b] - 1], 1);
    perm[pos] = b;
}

// ---------------- Kernel A: fused LSTM ----------------
// 256 blocks x 768 threads (12 waves, 3/SIMD). Block owns 8 length-sorted
// batch rows (perm). Runs only t < bmax = max(len in block).
// Phase 1 (all 12 waves): wave w computes gate-tiles {2w, 2w+1}, C init =
//   bias, writes raw gates to sgate[gcol*8 + b] (ds_write_b128, quads 0-1;
//   A rows 8-15 are zero padding).
// Phase 3' (after barrier1, overlaps phase2): coop-store h(t-1) (already
//   barrier-ordered) LDS->global, coalesced dwords. H rows t>=len hold the
//   frozen h / poison — attn kernel is gated on t<len so they're never used.
// Phase 2: lane -> (u=tid>>3, b=tid&7) reads i/f/g/o from sgate, activations,
//   writes fp16 h to sh[buf^1].
__global__ __launch_bounds__(768, 1) void lstm_kernel(
    const float* __restrict__ x, const int* __restrict__ lengths,
    const int* __restrict__ perm,
    const float* __restrict__ Wih, const float* __restrict__ Whh,
    const float* __restrict__ bih, const float* __restrict__ bhh,
    _Float16* __restrict__ Hout, float* __restrict__ hT)
{
    __shared__ float sgate[NG_ * GS];       // 12288 B, raw gates [gcol][b]
    __shared__ _Float16 sh[2][16 * HP];     // 6656 B, h double buffer [b][u]
    __shared__ int sgb[BPB], slen[BPB];

    const int tid  = threadIdx.x;
    const int bb   = blockIdx.x * BPB;
    const int wave = tid >> 6;
    const int lane = tid & 63;
    const int col  = lane & 15;
    const int quad = lane >> 4;

    if (tid < BPB) {
        const int g = perm[bb + tid];
        sgb[tid] = g;
        slen[tid] = lengths[g];
    }
    // zero h buffers (rows 8-15 stay zero forever)
    {
        _Float16* shf = &sh[0][0];
        for (int i = tid; i < 2 * 16 * HP; i += 768) shf[i] = (_Float16)0.f;
    }
    __syncthreads();

    int bmax = slen[0];
#pragma unroll
    for (int i = 1; i < BPB; ++i) bmax = max(bmax, slen[i]);

    // ---- MFMA role: 2 gate tiles per wave
    int gc[2]; float bias[2];
    f16x8 wh[2][3], wi[2];
#pragma unroll
    for (int j = 0; j < 2; ++j) {
        const int tau = wave * 2 + j;
        const int g = tau / 6, u6 = tau % 6;
        const int gcj = g * DH_ + u6 * 16 + col;
        gc[j] = gcj;
#pragma unroll
        for (int kf = 0; kf < 3; ++kf)
            wh[j][kf] = cvt8p(Whh + gcj * DH_ + kf * 32 + quad * 8);
        wi[j] = cvt8p(Wih + gcj * DIN_ + quad * 8);
        bias[j] = bih[gcj] + bhh[gcj];
    }

    // ---- epilogue role: one (unit, batch) pair per lane
    const int eu = tid >> 3;          // 0..95
    const int eb = tid & 7;           // 0..7
    float c1 = 0.f, hk1 = 0.f;
    const int len1 = slen[eb];

    // ---- coop-store role
    const bool st_act = tid < 384;
    const int sb = tid / 48;                  // batch row 0..7
    const int su = (tid % 48) * 2;            // unit pair
    _Float16* Hst = Hout + ((long long)sgb[sb] * T_) * DH_ + su;

    // ---- x prefetch (A-fragment rows = permuted batches; rows 8-15 padding)
    const float* xp = x + ((long long)sgb[col & 7] * T_) * DIN_ + quad * 8;
    float4 xc0 = *(const float4*)xp;
    float4 xc1 = *(const float4*)(xp + 4);

    for (int t = 0; t < bmax; ++t) {
        const int buf = t & 1;

        // ---------- phase 1: MFMA (all waves) ----------
        const _Float16* hrow = &sh[buf][col * HP];
        f16x8 h0 = *(const f16x8*)(hrow + 0  + quad * 8);
        f16x8 h1 = *(const f16x8*)(hrow + 32 + quad * 8);
        f16x8 h2 = *(const f16x8*)(hrow + 64 + quad * 8);

        // prefetch x(t+1)
        const float* xpn = (t + 1 < T_) ? (xp + DIN_) : xp;
        float4 xn0 = *(const float4*)xpn;
        float4 xn1 = *(const float4*)(xpn + 4);

        f16x8 xa = cvt8(xc0, xc1);

#pragma unroll
        for (int j = 0; j < 2; ++j) {
            f32x4 a = {bias[j], bias[j], bias[j], bias[j]};
            a = __builtin_amdgcn_mfma_f32_16x16x32_f16(h0, wh[j][0], a, 0, 0, 0);
            a = __builtin_amdgcn_mfma_f32_16x16x32_f16(h1, wh[j][1], a, 0, 0, 0);
            a = __builtin_amdgcn_mfma_f32_16x16x32_f16(h2, wh[j][2], a, 0, 0, 0);
            a = __builtin_amdgcn_mfma_f32_16x16x32_f16(xa, wi[j],    a, 0, 0, 0);
            if (quad < 2)   // rows 0-7 real batch; 8-15 padding
                *(f32x4*)&sgate[gc[j] * GS + quad * 4] = a;
        }
        lds_barrier();   // gates visible (also orders prev step's h writes)

        // ---------- phase 3': coop-store h(t-1), overlaps phase 2 ----------
        if (t > 0 && st_act) {
            unsigned v = *(const unsigned*)&sh[buf][sb * HP + su];
            *(unsigned*)Hst = v;
            Hst += DH_;
        }

        // ---------- phase 2: epilogue (one pair per lane) ----------
        {
            float iv = sgate[(0 * DH_ + eu) * GS + eb];
            float fv = sgate[(1 * DH_ + eu) * GS + eb];
            float gv = sgate[(2 * DH_ + eu) * GS + eb];
            float ov = sgate[(3 * DH_ + eu) * GS + eb];
            float cn = sigf(fv) * c1 + sigf(iv) * tanhf_(gv);
            float hn = sigf(ov) * tanhf_(cn);
            const bool m = t < len1;
            c1  = m ? cn : c1;
            hk1 = m ? hn : hk1;
            sh[buf ^ 1][eb * HP + eu] = (_Float16)hk1;
        }
        lds_barrier();   // h(t) visible

        xp = xpn; xc0 = xn0; xc1 = xn1;
    }

    // final H column t = bmax-1
    if (st_act) {
        unsigned v = *(const unsigned*)&sh[bmax & 1][sb * HP + su];
        *(unsigned*)Hst = v;
    }

    hT[sgb[eb] * DH_ + eu] = hk1;
}

// ---------------- Kernel B: per-batch Q, qk = (Wk^T Q)/sqrt(DH), qb = (Q.bk)/sqrt(DH)
__global__ __launch_bounds__(128) void qk_kernel(
    const float* __restrict__ hT, const float* __restrict__ Wq,
    const float* __restrict__ bq, const float* __restrict__ Wk,
    const float* __restrict__ bk, float* __restrict__ qk_out,
    float* __restrict__ qb_out)
{
    __shared__ float shT[DH_], sQ[DH_];
    const int b = blockIdx.x, tid = threadIdx.x;
    const float scale = 0.10206207262f; // 1/sqrt(96)
    if (tid < DH_) shT[tid] = hT[b * DH_ + tid];
    __syncthreads();
    if (tid < DH_) {
        float acc = bq[tid];
        const float* wr = Wq + tid * DH_;
        for (int d = 0; d < DH_; d += 4) {
            float4 w4 = *(const float4*)(wr + d);
            acc += w4.x * shT[d] + w4.y * shT[d + 1] + w4.z * shT[d + 2] + w4.w * shT[d + 3];
        }
        sQ[tid] = acc;
    }
    __syncthreads();
    if (tid < DH_) {
        float acc = 0.f;
        for (int j = 0; j < DH_; ++j) acc += Wk[j * DH_ + tid] * sQ[j];
        qk_out[b * DH_ + tid] = acc * scale;
    }
    if (tid == 0) {
        float acc = 0.f;
        for (int d = 0; d < DH_; ++d) acc += sQ[d] * bk[d];
        qb_out[b] = acc * scale;
    }
}

// ---------------- Kernel C: logits/softmax/ctx + MoE head. One block per batch.
// Gated on t < len everywhere H is read (H rows t>=len are unwritten).
__global__ __launch_bounds__(512) void attn_moe_kernel(
    const _Float16* __restrict__ H, const float* __restrict__ hT,
    const float* __restrict__ qk, const float* __restrict__ qb,
    const int* __restrict__ lengths,
    const float* __restrict__ Wv, const float* __restrict__ bv,
    const float* __restrict__ Wg, const float* __restrict__ bg,
    const float* __restrict__ We1, const float* __restrict__ be1,
    const float* __restrict__ We2, const float* __restrict__ be2,
    float* __restrict__ yhat_out, float* __restrict__ alpha_out,
    float* __restrict__ gl_out)
{
    __shared__ float salpha[T_];
    __shared__ float sqk[DH_];
    __shared__ float spart[4 * DH_];
    __shared__ float sfeats[2 * DH_];
    __shared__ float sh1[2][DH_];
    __shared__ float sred[8], ssum[8];
    __shared__ float sgl[E_];
    __shared__ float spi[2];
    __shared__ int stopi[2];

    const int b = blockIdx.x, tid = threadIdx.x;
    const int len = lengths[b];
    if (tid < DH_) sqk[tid] = qk[b * DH_ + tid];
    const float qbv = qb[b];
    __syncthreads();

    // logits: thread t (only t < len reads H)
    const bool valid = tid < len;
    float l = qbv;
    if (valid) {
        const _Float16* hr = H + ((long long)b * T_ + tid) * DH_;
#pragma unroll
        for (int u = 0; u < DH_; u += 8) {
            f16x8 hv = *(const f16x8*)(hr + u);
            float4 qa = *(const float4*)&sqk[u];
            float4 qc = *(const float4*)&sqk[u + 4];
            l += (float)hv[0] * qa.x + (float)hv[1] * qa.y
               + (float)hv[2] * qa.z + (float)hv[3] * qa.w
               + (float)hv[4] * qc.x + (float)hv[5] * qc.y
               + (float)hv[6] * qc.z + (float)hv[7] * qc.w;
        }
    }
    float lv = valid ? l : -1e30f;

    float m = lv;
    for (int off = 32; off; off >>= 1) m = fmaxf(m, __shfl_xor(m, off));
    if ((tid & 63) == 0) sred[tid >> 6] = m;
    __syncthreads();
    m = sred[0];
#pragma unroll
    for (int i = 1; i < 8; ++i) m = fmaxf(m, sred[i]);

    float e = valid ? EXP2F((l - m) * 1.44269504f) : 0.f;
    float s = e;
    for (int off = 32; off; off >>= 1) s += __shfl_xor(s, off);
    if ((tid & 63) == 0) ssum[tid >> 6] = s;
    __syncthreads();
    s = ssum[0];
#pragma unroll
    for (int i = 1; i < 8; ++i) s += ssum[i];

    const float alpha = e * RCPF(s);
    salpha[tid] = alpha;
    alpha_out[(long long)b * T_ + tid] = alpha;
    __syncthreads();

    // ctx raw partials: 4 t-chunks x 96 units, gated to t < len
    if (tid < 4 * DH_) {
        const int s4 = tid / DH_, u = tid - s4 * DH_;
        float acc = 0.f;
        const int t0 = s4 * 128, t1 = min(t0 + 128, len);
        const _Float16* hc = H + ((long long)b * T_) * DH_ + u;
        for (int t = t0; t < t1; ++t)
            acc += salpha[t] * (float)hc[t * DH_];
        spart[s4 * DH_ + u] = acc;
    }
    __syncthreads();
    if (tid < DH_) {
        float craw = spart[tid] + spart[DH_ + tid] + spart[2 * DH_ + tid] + spart[3 * DH_ + tid];
        spart[tid] = craw;
    }
    __syncthreads();
    if (tid < DH_) {
        float acc = bv[tid];
        const float* wr = Wv + tid * DH_;
        for (int u = 0; u < DH_; u += 4) {
            float4 w4 = *(const float4*)(wr + u);
            acc += w4.x * spart[u] + w4.y * spart[u + 1] + w4.z * spart[u + 2] + w4.w * spart[u + 3];
        }
        sfeats[tid] = acc;             // ctx
        sfeats[DH_ + tid] = hT[b * DH_ + tid];
    }
    __syncthreads();

    // gate logits: 6 experts x 32 lanes, 6 f-elems per lane
    if (tid < 192) {
        const int e6 = tid >> 5, cc = tid & 31;
        float p = 0.f;
        const float* wg = Wg + e6 * 2 * DH_;
#pragma unroll
        for (int j = 0; j < 6; ++j) p += wg[cc * 6 + j] * sfeats[cc * 6 + j];
        for (int off = 16; off; off >>= 1) p += __shfl_xor(p, off);
        if (cc == 0) {
            float g = p + bg[e6];
            sgl[e6] = g;
            gl_out[b * E_ + e6] = g;
        }
    }
    __syncthreads();

    if (tid == 0) {
        int i0 = 0; float v0 = sgl[0];
        for (int ee = 1; ee < E_; ++ee) if (sgl[ee] > v0) { v0 = sgl[ee]; i0 = ee; }
        int i1 = -1; float v1 = -1e30f;
        for (int ee = 0; ee < E_; ++ee) {
            if (ee == i0) continue;
            if (sgl[ee] > v1) { v1 = sgl[ee]; i1 = ee; }
        }
        float e1 = EXP2F((v1 - v0) * 1.44269504f);
        float inv = RCPF(1.f + e1);
        spi[0] = inv; spi[1] = e1 * inv;
        stopi[0] = i0; stopi[1] = i1;
    }
    __syncthreads();

    // expert hidden for the 2 selected experts
    if (tid < 192) {
        const int e2 = tid / DH_, u = tid - e2 * DH_;
        const int ex = stopi[e2];
        float acc = be1[ex * DH_ + u];
        const float* w = We1 + ((long long)ex * DH_ + u) * (2 * DH_);
        for (int f = 0; f < 2 * DH_; f += 4) {
            float4 w4 = *(const float4*)(w + f);
            acc += w4.x * sfeats[f] + w4.y * sfeats[f + 1] + w4.z * sfeats[f + 2] + w4.w * sfeats[f + 3];
        }
        sh1[e2][u] = fmaxf(acc, 0.f);
    }
    __syncthreads();

    if (tid == 0) {
        float outs[2];
#pragma unroll
        for (int e2 = 0; e2 < 2; ++e2) {
            const int ex = stopi[e2];
            float a = be2[ex];
            for (int u = 0; u < DH_; ++u) a += sh1[e2][u] * We2[ex * DH_ + u];
            outs[e2] = a;
        }
        yhat_out[b] = spi[0] * outs[0] + spi[1] * outs[1];
    }
}

extern "C" void kernel_launch(void* const* d_in, const int* in_sizes, int n_in,
                              void* d_out, int out_size, void* d_ws, size_t ws_size,
                              hipStream_t stream) {
    const float* x   = (const float*)d_in[0];
    const int* lengths = (const int*)d_in[1];
    // d_in[2] = mask (recomputed from lengths)
    const float* Wih = (const float*)d_in[3];
    const float* Whh = (const float*)d_in[4];
    const float* bih = (const float*)d_in[5];
    const float* bhh = (const float*)d_in[6];
    const float* Wq  = (const float*)d_in[7];
    const float* bq  = (const float*)d_in[8];
    const float* Wk  = (const float*)d_in[9];
    const float* bk  = (const float*)d_in[10];
    const float* Wv  = (const float*)d_in[11];
    const float* bv  = (const float*)d_in[12];
    const float* Wg  = (const float*)d_in[13];
    const float* bg  = (const float*)d_in[14];
    const float* We1 = (const float*)d_in[15];
    const float* be1 = (const float*)d_in[16];
    const float* We2 = (const float*)d_in[17];
    const float* be2 = (const float*)d_in[18];

    float* yhat  = (float*)d_out;
    float* alpha = yhat + B_;
    float* gl    = alpha + (size_t)B_ * T_;

    char* ws = (char*)d_ws;
    _Float16* Hws = (_Float16*)ws;                                   // B*T*96 fp16
    float* hTws = (float*)(ws + (size_t)B_ * T_ * DH_ * 2);          // B*96 f32
    float* qkws = hTws + (size_t)B_ * DH_;                           // B*96 f32
    float* qbws = qkws + (size_t)B_ * DH_;                           // B f32
    int* bins   = (int*)(qbws + B_);                                 // 512
    int* offs   = bins + 512;                                        // 512
    int* perm   = offs + 512;                                        // B

    sort_zero_kernel<<<dim3(1), dim3(512), 0, stream>>>(bins);
    sort_count_kernel<<<dim3(B_ / 256), dim3(256), 0, stream>>>(lengths, bins);
    sort_scan_kernel<<<dim3(1), dim3(512), 0, stream>>>(bins, offs);
    sort_place_kernel<<<dim3(B_ / 256), dim3(256), 0, stream>>>(lengths, offs, perm);

    lstm_kernel<<<dim3(B_ / BPB), dim3(768), 0, stream>>>(
        x, lengths, perm, Wih, Whh, bih, bhh, Hws, hTws);
    qk_kernel<<<dim3(B_), dim3(128), 0, stream>>>(
        hTws, Wq, bq, Wk, bk, qkws, qbws);
    attn_moe_kernel<<<dim3(B_), dim3(512), 0, stream>>>(
        Hws, hTws, qkws, qbws, lengths, Wv, bv, Wg, bg,
        We1, be1, We2, be2, yhat, alpha, gl);
}